// Round 2
// baseline (612.888 us; speedup 1.0000x reference)
//
#include <hip/hip_runtime.h>

#define NN 8192
#define STEPS 64
#define DECAYF 0.9f
#define THRESHF 1.0f
#define K_MAX 384            // ELL row capacity = 2 segments x 192
#define K_SEG 192            // per-half-row segment (nnz ~129 +/- 11, +5.6 sigma)
#define KITER 24             // 384 / 16 lanes per row

#define CBLOCKS 256          // one block per CU; regular launch
#define STHREADS 576         // 9 waves: wave 0 = poller, 1..8 compute+publish
#define MBSTRIDE 1           // DENSE mailbox: 8 B per entry (R15)

typedef unsigned long long u64;
typedef unsigned int u32;

// Relaxed agent-scope accesses: bypass L1/L2, coherent at L3.
// One aligned u64 = (step_tag<<32 | fire_bits): publish == barrier-arrive.
// R15: (a) REVERT depth-2 staggered polling (R14 regression: checking the
//      previous round's value added one full poll period of staleness,
//      +28 us measured). Fresh-check poller restored.
//      (b) DENSE mailbox (stride 8 B, was 128 B): each poll instruction
//      coalesces the wave into 512 B contiguous segments -> ~8-16x less L3
//      line traffic (256 scattered lines -> 32 dense lines per round),
//      relieving L3 slice oversubscription that inflates poll latency.
//      (c) s_sleep(1) backoff (less traffic -> less need for backoff).
//      Kept from R14: fetch_or publish merge; extract_ell register prefetch.
__device__ __forceinline__ void pub_store(u64* p, u64 v) {
    __hip_atomic_store(p, v, __ATOMIC_RELAXED, __HIP_MEMORY_SCOPE_AGENT);
}
__device__ __forceinline__ u64 pub_load(const u64* p) {
    return __hip_atomic_load(p, __ATOMIC_RELAXED, __HIP_MEMORY_SCOPE_AGENT);
}

// ---------------------------------------------------------------------------
// Dispatch 1: W -> packed global ELL. One wave per HALF-row (4096 cols).
// All 16 float4 loads issued up-front (register prefetch), then the serial
// ballot-chain compaction runs on register data.
// ---------------------------------------------------------------------------
__global__ __launch_bounds__(256) void extract_ell(
        const float* __restrict__ W,
        u64* __restrict__ pk) {          // [NN][K_MAX] = (col<<32)|f32bits
    const int wave = threadIdx.x >> 6;
    const int lane = threadIdx.x & 63;
    const int hrow = blockIdx.x * 4 + wave;      // 0..16383
    const int row  = hrow >> 1;
    const int half = hrow & 1;
    const int cbase = half * (NN / 2);           // column offset of this half

    const float4* wr4 = (const float4*)(W + (size_t)row * NN + cbase);
    u64* pr = pk + (size_t)row * K_MAX + half * K_SEG;
    const u64 lmask = (1ull << lane) - 1ull;

    float4 wv[16];
    #pragma unroll
    for (int i = 0; i < 16; ++i)
        wv[i] = wr4[lane + 64 * i];              // 16 loads in flight

    int base = 0;
    #pragma unroll
    for (int i = 0; i < 16; ++i) {
        const int col0 = cbase + (lane + 64 * i) * 4;
        #pragma unroll
        for (int comp = 0; comp < 4; ++comp) {
            float val = (comp == 0) ? wv[i].x : (comp == 1) ? wv[i].y
                      : (comp == 2) ? wv[i].z : wv[i].w;
            u64 m = __ballot(val != 0.0f);
            if (val != 0.0f) {
                int idx = base + __popcll(m & lmask);
                if (idx < K_SEG)                 // +5.6 sigma guard
                    pr[idx] = ((u64)(u32)(col0 + comp) << 32)
                            | (u64)__float_as_uint(val);
            }
            base += __popcll(m);
        }
    }
    const int cap = (base < K_SEG) ? base : K_SEG;
    for (int j = cap + lane; j < K_SEG; j += 64) pr[j] = 0ull;
}

// ---------------------------------------------------------------------------
// Dispatch 2: persistent step kernel. ELL in VGPRs, dense mailbox,
// fresh-check poller, fetch_or publish merge.
// ---------------------------------------------------------------------------
__global__ __launch_bounds__(STHREADS) void spiking_steps(
        const u64* __restrict__ pk,
        const float* __restrict__ f0,
        const float* __restrict__ v0,
        float* __restrict__ out,
        u64* __restrict__ fdata) {       // [2][CBLOCKS] dense u64 entries
    __shared__ u32 lds_fbits[2][CBLOCKS];    // 2 KB, dbuf by parity
    __shared__ u32 lds_word[STEPS];          // merged fire nibbles per step
    __shared__ int lds_cnt[STEPS];           // per-step arrive counters
    __shared__ int lds_flag;                 // monotonic: inputs ready

    const int tid  = threadIdx.x;
    const int wave = tid >> 6;
    const int lane = tid & 63;
    const int bid  = blockIdx.x;

    if (tid < STEPS) { lds_cnt[tid] = 0; lds_word[tid] = 0u; }
    if (tid == 0) lds_flag = 0;

    // publish own f0 word (tag 1, slot 0) ASAP
    if (wave == 0) {
        float f = (lane < 32) ? f0[bid * 32 + lane] : 0.0f;
        u64 m = __ballot(f != 0.0f);
        if (lane == 0)
            pub_store(&fdata[bid],
                      (1ull << 32) | (u32)(m & 0xffffffffull));
    }
    __syncthreads();   // only barrier (control-var init)

    if (wave == 0) {
        // ===== PURE POLLER: fresh-check, incremental stash, light backoff ===
        for (int s = 0; s < STEPS; ++s) {
            const u64* slot = fdata + (size_t)(s & 1) * CBLOCKS;
            const u32 want = (u32)(s + 1);
            u32* fb = lds_fbits[s & 1];
            u32 pend = 0xFu;                 // 4 words per lane outstanding
            for (;;) {
                #pragma unroll
                for (int k = 0; k < 4; ++k) {
                    if ((pend >> k) & 1u) {
                        u64 w = pub_load(&slot[lane + 64 * k]);
                        if ((u32)(w >> 32) == want) {
                            fb[lane + 64 * k] = (u32)w;   // stash on arrival
                            pend &= ~(1u << k);
                        }
                    }
                }
                if (__all(pend == 0)) break;
                __builtin_amdgcn_s_sleep(1);   // ~64 cyc light backoff
            }
            if (lane == 0)
                __hip_atomic_store(&lds_flag, s + 1, __ATOMIC_RELEASE,
                                   __HIP_MEMORY_SCOPE_WORKGROUP);
        }
    } else {
        // ===== COMPUTE (waves 1..8, 4 rows each); last arriver publishes =====
        const int g    = wave - 1;               // 0..7
        const int rloc = g * 4 + (lane >> 4);    // local row 0..31
        const int row  = bid * 32 + rloc;
        const int l16  = lane & 15;

        u32 ecol[KITER]; float eval[KITER];
        const u64* pr = pk + (size_t)row * K_MAX;
        #pragma unroll
        for (int k = 0; k < KITER; ++k) {
            u64 p = pr[l16 + 16 * k];
            ecol[k] = (u32)(p >> 32);
            eval[k] = __uint_as_float((u32)p);
        }
        float vreg = v0[row];                    // identical across the 16 lanes

        for (int s = 0; s < STEPS; ++s) {
            while (__hip_atomic_load(&lds_flag, __ATOMIC_ACQUIRE,
                                     __HIP_MEMORY_SCOPE_WORKGROUP) < s + 1) {}
            const u32* fb = lds_fbits[s & 1];

            // gather with 3 independent fp64 accumulators (short dep chains)
            double a0 = 0.0, a1 = 0.0, a2 = 0.0;
            #pragma unroll
            for (int k = 0; k < KITER; k += 3) {
                u32 c0 = ecol[k],     w0 = fb[c0 >> 5];
                u32 c1 = ecol[k + 1], w1 = fb[c1 >> 5];
                u32 c2 = ecol[k + 2], w2 = fb[c2 >> 5];
                a0 += (double)(((w0 >> (c0 & 31)) & 1u) ? eval[k]     : 0.0f);
                a1 += (double)(((w1 >> (c1 & 31)) & 1u) ? eval[k + 1] : 0.0f);
                a2 += (double)(((w2 >> (c2 & 31)) & 1u) ? eval[k + 2] : 0.0f);
            }
            double acc = (a0 + a1) + a2;
            #pragma unroll
            for (int m = 8; m >= 1; m >>= 1)     // 16-lane butterfly
                acc += __shfl_xor(acc, m, 64);

            float u  = (float)acc;
            float vv = __fadd_rn(__fmul_rn(DECAYF, vreg), u);
            int fire = (vv >= THRESHF);
            vreg = fire ? 0.0f : vv;

            // ---- publish path FIRST (critical chain), out[] store after ----
            u64 bal = __ballot(fire);            // uniform within 16-lane groups
            if (lane == 0) {
                u32 bits4 = ((u32)(bal       ) & 1u)
                          | (((u32)(bal >> 16) & 1u) << 1)
                          | (((u32)(bal >> 32) & 1u) << 2)
                          | (((u32)(bal >> 48) & 1u) << 3);
                __hip_atomic_fetch_or(&lds_word[s], bits4 << (4 * g),
                                      __ATOMIC_ACQ_REL,
                                      __HIP_MEMORY_SCOPE_WORKGROUP);
                int old = __hip_atomic_fetch_add(&lds_cnt[s], 1, __ATOMIC_ACQ_REL,
                                                 __HIP_MEMORY_SCOPE_WORKGROUP);
                if (old == 7) {                  // 8th (last) compute wave
                    // all 8 fetch_or's happen-before the winning fetch_add
                    u32 b = __hip_atomic_load(&lds_word[s], __ATOMIC_ACQUIRE,
                                              __HIP_MEMORY_SCOPE_WORKGROUP);
                    pub_store(&fdata[(size_t)((s + 1) & 1) * CBLOCKS + bid],
                              ((u64)(u32)(s + 2) << 32) | b);
                }
            }

            if (l16 == 0)
                out[(size_t)s * NN + row] = fire ? 1.0f : 0.0f;
        }
    }
}

extern "C" void kernel_launch(void* const* d_in, const int* in_sizes, int n_in,
                              void* d_out, int out_size, void* d_ws, size_t ws_size,
                              hipStream_t stream) {
    const float* W  = (const float*)d_in[0];
    const float* f0 = (const float*)d_in[1];
    const float* v0 = (const float*)d_in[2];
    float* out = (float*)d_out;

    // workspace: packed ELL (25.2 MB) | dense mailbox (4 KB)
    u64* pk    = (u64*)d_ws;
    u64* fdata = pk + (size_t)NN * K_MAX;   // 0xAA poison != any tag 1..66

    extract_ell<<<dim3(NN * 2 / 4), dim3(256), 0, stream>>>(W, pk);
    spiking_steps<<<dim3(CBLOCKS), dim3(STHREADS), 0, stream>>>(
        pk, f0, v0, out, fdata);
}

// Round 3
// 558.748 us; speedup vs baseline: 1.0969x; 1.0969x over previous
//
#include <hip/hip_runtime.h>

#define NN 8192
#define STEPS 64
#define DECAYF 0.9f
#define THRESHF 1.0f
#define K_MAX 384            // ELL row capacity = 2 segments x 192
#define K_SEG 192            // per-half-row segment (nnz ~129 +/- 11, +5.6 sigma)
#define KITER 24             // 384 / 16 lanes per row
#define LROWS 32             // rows per block
#define LPITCH 385           // LDS ELL row pitch in u64 (+1 pad: bank spread)

#define CBLOCKS 256          // one block per CU; regular launch
#define STHREADS 576         // 9 waves: wave 0 = poller, 1..8 compute+publish
#define MBSTRIDE 16          // u64 per mailbox entry = 128 B: one line per word
                             // (R15 dense-mailbox regressed +48us: publisher
                             //  stores serialize on shared-line ownership)

typedef unsigned long long u64;
typedef unsigned int u32;

// Relaxed agent-scope accesses: coherent at L3.
// One aligned u64 = (step_tag<<32 | fire_bits): publish == barrier-arrive.
// R16: FUSE extraction into the persistent kernel. Each block extracts its
//      own 32 rows of W into LDS ELL (98.5 KB), compute waves pull their
//      fragments LDS->VGPR. Eliminates the extract_ell dispatch and the
//      50 MB pk write+read; extraction overlaps the f0 mailbox exchange.
//      Step loop restored VERBATIM to the proven R13 config (198.6 us):
//      padded mailbox, fresh-check poll, s_sleep(2), shuffle-merge publish.
__device__ __forceinline__ void pub_store(u64* p, u64 v) {
    __hip_atomic_store(p, v, __ATOMIC_RELAXED, __HIP_MEMORY_SCOPE_AGENT);
}
__device__ __forceinline__ u64 pub_load(const u64* p) {
    return __hip_atomic_load(p, __ATOMIC_RELAXED, __HIP_MEMORY_SCOPE_AGENT);
}

__global__ __launch_bounds__(STHREADS) void spiking_fused(
        const float* __restrict__ W,
        const float* __restrict__ f0,
        const float* __restrict__ v0,
        float* __restrict__ out,
        u64* __restrict__ fdata) {       // [2][CBLOCKS][MBSTRIDE]
    __shared__ u64 lds_ell[LROWS * LPITCH];  // 98.5 KB packed ELL, this block
    __shared__ u32 lds_fbits[2][CBLOCKS];    // 2 KB, dbuf by parity
    __shared__ u32 lds_spike[8];             // bits4 per compute wave
    __shared__ int lds_cnt[STEPS];           // per-step arrive counters
    __shared__ int lds_flag;                 // monotonic: inputs ready

    const int tid  = threadIdx.x;
    const int wave = tid >> 6;
    const int lane = tid & 63;
    const int bid  = blockIdx.x;

    if (tid < STEPS) lds_cnt[tid] = 0;
    if (tid == 0) lds_flag = 0;

    // publish own f0 word (tag 1, slot 0) ASAP — lands while we extract
    if (wave == 0) {
        float f = (lane < 32) ? f0[bid * 32 + lane] : 0.0f;
        u64 m = __ballot(f != 0.0f);
        if (lane == 0)
            pub_store(&fdata[(size_t)bid * MBSTRIDE],
                      (1ull << 32) | (u32)(m & 0xffffffffull));
    }

    // ===== Phase 0: all 9 waves extract this block's 32 rows -> LDS ELL ====
    // 64 half-rows / 9 waves; each half-row = 4096 cols = 16 float4/lane.
    {
        const u64 lmask = (1ull << lane) - 1ull;
        for (int hr = wave; hr < 2 * LROWS; hr += 9) {
            const int rloc = hr >> 1;
            const int half = hr & 1;
            const int cbase = half * (NN / 2);
            const float4* wr4 = (const float4*)
                (W + (size_t)(bid * LROWS + rloc) * NN + cbase);
            u64* pr = lds_ell + rloc * LPITCH + half * K_SEG;

            float4 wv[16];
            #pragma unroll
            for (int i = 0; i < 16; ++i)
                wv[i] = wr4[lane + 64 * i];          // 16 KB in flight

            int base = 0;
            #pragma unroll
            for (int i = 0; i < 16; ++i) {
                const int col0 = cbase + (lane + 64 * i) * 4;
                #pragma unroll
                for (int comp = 0; comp < 4; ++comp) {
                    float val = (comp == 0) ? wv[i].x : (comp == 1) ? wv[i].y
                              : (comp == 2) ? wv[i].z : wv[i].w;
                    u64 m = __ballot(val != 0.0f);
                    if (val != 0.0f) {
                        int idx = base + __popcll(m & lmask);
                        if (idx < K_SEG)             // +5.6 sigma guard
                            pr[idx] = ((u64)(u32)(col0 + comp) << 32)
                                    | (u64)__float_as_uint(val);
                    }
                    base += __popcll(m);
                }
            }
            const int cap = (base < K_SEG) ? base : K_SEG;
            for (int j = cap + lane; j < K_SEG; j += 64) pr[j] = 0ull;
        }
    }
    __syncthreads();   // only barrier: ELL + control vars ready

    if (wave == 0) {
        // ===== PURE POLLER (R13 verbatim): fresh-check, stash, backoff =====
        for (int s = 0; s < STEPS; ++s) {
            const u64* slot = fdata + (size_t)(s & 1) * CBLOCKS * MBSTRIDE;
            const u32 want = (u32)(s + 1);
            u32* fb = lds_fbits[s & 1];
            u32 pend = 0xFu;                 // 4 words per lane outstanding
            for (;;) {
                #pragma unroll
                for (int k = 0; k < 4; ++k) {
                    if ((pend >> k) & 1u) {
                        u64 w = pub_load(&slot[(size_t)(lane + 64 * k) * MBSTRIDE]);
                        if ((u32)(w >> 32) == want) {
                            fb[lane + 64 * k] = (u32)w;   // stash on arrival
                            pend &= ~(1u << k);
                        }
                    }
                }
                if (__all(pend == 0)) break;
                __builtin_amdgcn_s_sleep(2);   // ~128 cyc: cut L3 read pressure
            }
            if (lane == 0)
                __hip_atomic_store(&lds_flag, s + 1, __ATOMIC_RELEASE,
                                   __HIP_MEMORY_SCOPE_WORKGROUP);
        }
    } else {
        // ===== COMPUTE (waves 1..8, 4 rows each); last wave publishes =====
        const int g    = wave - 1;               // 0..7
        const int rloc = g * 4 + (lane >> 4);    // local row 0..31
        const int row  = bid * LROWS + rloc;
        const int l16  = lane & 15;

        // one-time LDS ELL -> registers (replaces the old global pk reload)
        u32 ecol[KITER]; float eval[KITER];
        const u64* pr = lds_ell + rloc * LPITCH;
        #pragma unroll
        for (int k = 0; k < KITER; ++k) {
            u64 p = pr[l16 + 16 * k];
            ecol[k] = (u32)(p >> 32);
            eval[k] = __uint_as_float((u32)p);
        }
        float vreg = v0[row];                    // identical across the 16 lanes

        for (int s = 0; s < STEPS; ++s) {
            while (__hip_atomic_load(&lds_flag, __ATOMIC_ACQUIRE,
                                     __HIP_MEMORY_SCOPE_WORKGROUP) < s + 1) {}
            const u32* fb = lds_fbits[s & 1];

            // gather with 3 independent fp64 accumulators (short dep chains)
            double a0 = 0.0, a1 = 0.0, a2 = 0.0;
            #pragma unroll
            for (int k = 0; k < KITER; k += 3) {
                u32 c0 = ecol[k],     w0 = fb[c0 >> 5];
                u32 c1 = ecol[k + 1], w1 = fb[c1 >> 5];
                u32 c2 = ecol[k + 2], w2 = fb[c2 >> 5];
                a0 += (double)(((w0 >> (c0 & 31)) & 1u) ? eval[k]     : 0.0f);
                a1 += (double)(((w1 >> (c1 & 31)) & 1u) ? eval[k + 1] : 0.0f);
                a2 += (double)(((w2 >> (c2 & 31)) & 1u) ? eval[k + 2] : 0.0f);
            }
            double acc = (a0 + a1) + a2;
            #pragma unroll
            for (int m = 8; m >= 1; m >>= 1)     // 16-lane butterfly
                acc += __shfl_xor(acc, m, 64);

            float u  = (float)acc;
            float vv = __fadd_rn(__fmul_rn(DECAYF, vreg), u);
            int fire = (vv >= THRESHF);
            vreg = fire ? 0.0f : vv;

            // ---- publish path FIRST (critical chain), out[] store after ----
            u64 bal = __ballot(fire);            // uniform within 16-lane groups
            int old = -1;
            if (lane == 0) {
                u32 bits4 = ((u32)(bal       ) & 1u)
                          | (((u32)(bal >> 16) & 1u) << 1)
                          | (((u32)(bal >> 32) & 1u) << 2)
                          | (((u32)(bal >> 48) & 1u) << 3);
                __hip_atomic_store(&lds_spike[g], bits4, __ATOMIC_RELAXED,
                                   __HIP_MEMORY_SCOPE_WORKGROUP);
                old = __hip_atomic_fetch_add(&lds_cnt[s], 1, __ATOMIC_ACQ_REL,
                                             __HIP_MEMORY_SCOPE_WORKGROUP);
            }
            old = __shfl(old, 0, 64);
            if (old == 7) {                      // 8th (last) compute wave
                u32 b = (lane < 8) ? ((lds_spike[lane] & 0xFu) << (4 * lane)) : 0u;
                b |= __shfl_xor(b, 1, 64);
                b |= __shfl_xor(b, 2, 64);
                b |= __shfl_xor(b, 4, 64);
                if (lane == 0)
                    pub_store(&fdata[((size_t)((s + 1) & 1) * CBLOCKS + bid) * MBSTRIDE],
                              ((u64)(u32)(s + 2) << 32) | b);
            }

            if (l16 == 0)
                out[(size_t)s * NN + row] = fire ? 1.0f : 0.0f;
        }
    }
}

extern "C" void kernel_launch(void* const* d_in, const int* in_sizes, int n_in,
                              void* d_out, int out_size, void* d_ws, size_t ws_size,
                              hipStream_t stream) {
    const float* W  = (const float*)d_in[0];
    const float* f0 = (const float*)d_in[1];
    const float* v0 = (const float*)d_in[2];
    float* out = (float*)d_out;

    // workspace: padded mailbox only (64 KB); 0xAA poison != any tag 1..66
    u64* fdata = (u64*)d_ws;

    spiking_fused<<<dim3(CBLOCKS), dim3(STHREADS), 0, stream>>>(
        W, f0, v0, out, fdata);
}

// Round 4
// 556.898 us; speedup vs baseline: 1.1005x; 1.0033x over previous
//
#include <hip/hip_runtime.h>

#define NN 8192
#define STEPS 64
#define DECAYF 0.9f
#define THRESHF 1.0f
#define K_MAX 384            // ELL row capacity = 2 segments x 192
#define K_SEG 192            // per-half-row segment (nnz ~129 +/- 11, +5.6 sigma)
#define KITER 24             // 384 / 16 lanes per row
#define LROWS 32             // rows per block
#define LPITCH 385           // LDS ELL row pitch in u64 (+1 pad: bank spread)

#define CBLOCKS 256          // one block per CU; regular launch
#define STHREADS 576         // 9 waves: wave 0 = poller, 1..8 compute+publish
#define MBSTRIDE 16          // u64 per mailbox entry = 128 B: one line per word
                             // (R15 dense-mailbox regressed +48us)

typedef unsigned long long u64;
typedef unsigned int u32;

// R17: software-pipelined extraction. R16 showed VGPR_Count=68 -> the
// compiler SANK the 16-float4 "prefetch" into the uses (64-reg array can't
// live in 68 regs); effective MLP was a few KB and extraction ran at
// ~1.3 TB/s (104 us vs ~50 floor). Now: two explicit 8-float4 buffers
// (32 VGPR each), chunk k+1 / next half-row chunk 0 loads issued BEFORE
// compacting chunk k, pinned with sched_barrier(0). 8 KB/wave always in
// flight -> stream-bound. Step loop: R13-verbatim (198.6 us measured).
__device__ __forceinline__ void pub_store(u64* p, u64 v) {
    __hip_atomic_store(p, v, __ATOMIC_RELAXED, __HIP_MEMORY_SCOPE_AGENT);
}
__device__ __forceinline__ u64 pub_load(const u64* p) {
    return __hip_atomic_load(p, __ATOMIC_RELAXED, __HIP_MEMORY_SCOPE_AGENT);
}

__global__ __launch_bounds__(STHREADS) void spiking_fused(
        const float* __restrict__ W,
        const float* __restrict__ f0,
        const float* __restrict__ v0,
        float* __restrict__ out,
        u64* __restrict__ fdata) {       // [2][CBLOCKS][MBSTRIDE]
    __shared__ u64 lds_ell[LROWS * LPITCH];  // 98.5 KB packed ELL, this block
    __shared__ u32 lds_fbits[2][CBLOCKS];    // 2 KB, dbuf by parity
    __shared__ u32 lds_spike[8];             // bits4 per compute wave
    __shared__ int lds_cnt[STEPS];           // per-step arrive counters
    __shared__ int lds_flag;                 // monotonic: inputs ready

    const int tid  = threadIdx.x;
    const int wave = tid >> 6;
    const int lane = tid & 63;
    const int bid  = blockIdx.x;

    if (tid < STEPS) lds_cnt[tid] = 0;
    if (tid == 0) lds_flag = 0;

    // publish own f0 word (tag 1, slot 0) ASAP — lands while we extract
    if (wave == 0) {
        float f = (lane < 32) ? f0[bid * 32 + lane] : 0.0f;
        u64 m = __ballot(f != 0.0f);
        if (lane == 0)
            pub_store(&fdata[(size_t)bid * MBSTRIDE],
                      (1ull << 32) | (u32)(m & 0xffffffffull));
    }

    // ===== Phase 0: pipelined extraction of 32 rows -> LDS ELL =============
    // 64 half-rows / 9 waves; half-row = 4096 cols = 2 chunks x 8 float4/lane.
    {
        const u64 lmask = (1ull << lane) - 1ull;
        const int HRT = 2 * LROWS;

        auto ld8 = [&](float4 (&cb)[8], int hr, int c) {
            const float4* wr4 = (const float4*)
                (W + (size_t)(bid * LROWS + (hr >> 1)) * NN
                   + (hr & 1) * (NN / 2));
            #pragma unroll
            for (int i = 0; i < 8; ++i)
                cb[i] = wr4[lane + 64 * (8 * c + i)];
            __builtin_amdgcn_sched_barrier(0);   // pin: no sinking past here
        };
        auto cp8 = [&](float4 (&cb)[8], int hr, int c, int& base) {
            const int cbase = (hr & 1) * (NN / 2);
            u64* pr = lds_ell + (hr >> 1) * LPITCH + (hr & 1) * K_SEG;
            #pragma unroll
            for (int i = 0; i < 8; ++i) {
                const int col0 = cbase + (lane + 64 * (8 * c + i)) * 4;
                #pragma unroll
                for (int comp = 0; comp < 4; ++comp) {
                    float val = (comp == 0) ? cb[i].x : (comp == 1) ? cb[i].y
                              : (comp == 2) ? cb[i].z : cb[i].w;
                    u64 m = __ballot(val != 0.0f);
                    if (val != 0.0f) {
                        int idx = base + __popcll(m & lmask);
                        if (idx < K_SEG)             // +5.6 sigma guard
                            pr[idx] = ((u64)(u32)(col0 + comp) << 32)
                                    | (u64)__float_as_uint(val);
                    }
                    base += __popcll(m);
                }
            }
        };

        float4 ca[8], cb[8];
        int hr = wave;
        if (hr < HRT) {
            ld8(ca, hr, 0);
            for (;;) {
                ld8(cb, hr, 1);                  // chunk 1 in flight
                int base = 0;
                cp8(ca, hr, 0, base);            // compact chunk 0
                const int hn = hr + 9;
                if (hn < HRT) ld8(ca, hn, 0);    // next half-row chunk 0
                cp8(cb, hr, 1, base);            // compact chunk 1
                {   // zero-pad this half-row's segment
                    u64* pr = lds_ell + (hr >> 1) * LPITCH + (hr & 1) * K_SEG;
                    const int cap = (base < K_SEG) ? base : K_SEG;
                    for (int j = cap + lane; j < K_SEG; j += 64) pr[j] = 0ull;
                }
                if (hn >= HRT) break;
                hr = hn;
            }
        }
    }
    __syncthreads();   // only barrier: ELL + control vars ready

    if (wave == 0) {
        // ===== PURE POLLER (R13 verbatim): fresh-check, stash, backoff =====
        for (int s = 0; s < STEPS; ++s) {
            const u64* slot = fdata + (size_t)(s & 1) * CBLOCKS * MBSTRIDE;
            const u32 want = (u32)(s + 1);
            u32* fb = lds_fbits[s & 1];
            u32 pend = 0xFu;                 // 4 words per lane outstanding
            for (;;) {
                #pragma unroll
                for (int k = 0; k < 4; ++k) {
                    if ((pend >> k) & 1u) {
                        u64 w = pub_load(&slot[(size_t)(lane + 64 * k) * MBSTRIDE]);
                        if ((u32)(w >> 32) == want) {
                            fb[lane + 64 * k] = (u32)w;   // stash on arrival
                            pend &= ~(1u << k);
                        }
                    }
                }
                if (__all(pend == 0)) break;
                __builtin_amdgcn_s_sleep(2);   // ~128 cyc: cut L3 read pressure
            }
            if (lane == 0)
                __hip_atomic_store(&lds_flag, s + 1, __ATOMIC_RELEASE,
                                   __HIP_MEMORY_SCOPE_WORKGROUP);
        }
    } else {
        // ===== COMPUTE (waves 1..8, 4 rows each); last wave publishes =====
        const int g    = wave - 1;               // 0..7
        const int rloc = g * 4 + (lane >> 4);    // local row 0..31
        const int row  = bid * LROWS + rloc;
        const int l16  = lane & 15;

        // one-time LDS ELL -> registers
        u32 ecol[KITER]; float eval[KITER];
        const u64* pr = lds_ell + rloc * LPITCH;
        #pragma unroll
        for (int k = 0; k < KITER; ++k) {
            u64 p = pr[l16 + 16 * k];
            ecol[k] = (u32)(p >> 32);
            eval[k] = __uint_as_float((u32)p);
        }
        float vreg = v0[row];                    // identical across the 16 lanes

        for (int s = 0; s < STEPS; ++s) {
            while (__hip_atomic_load(&lds_flag, __ATOMIC_ACQUIRE,
                                     __HIP_MEMORY_SCOPE_WORKGROUP) < s + 1) {}
            const u32* fb = lds_fbits[s & 1];

            // gather with 3 independent fp64 accumulators (short dep chains)
            double a0 = 0.0, a1 = 0.0, a2 = 0.0;
            #pragma unroll
            for (int k = 0; k < KITER; k += 3) {
                u32 c0 = ecol[k],     w0 = fb[c0 >> 5];
                u32 c1 = ecol[k + 1], w1 = fb[c1 >> 5];
                u32 c2 = ecol[k + 2], w2 = fb[c2 >> 5];
                a0 += (double)(((w0 >> (c0 & 31)) & 1u) ? eval[k]     : 0.0f);
                a1 += (double)(((w1 >> (c1 & 31)) & 1u) ? eval[k + 1] : 0.0f);
                a2 += (double)(((w2 >> (c2 & 31)) & 1u) ? eval[k + 2] : 0.0f);
            }
            double acc = (a0 + a1) + a2;
            #pragma unroll
            for (int m = 8; m >= 1; m >>= 1)     // 16-lane butterfly
                acc += __shfl_xor(acc, m, 64);

            float u  = (float)acc;
            float vv = __fadd_rn(__fmul_rn(DECAYF, vreg), u);
            int fire = (vv >= THRESHF);
            vreg = fire ? 0.0f : vv;

            // ---- publish path FIRST (critical chain), out[] store after ----
            u64 bal = __ballot(fire);            // uniform within 16-lane groups
            int old = -1;
            if (lane == 0) {
                u32 bits4 = ((u32)(bal       ) & 1u)
                          | (((u32)(bal >> 16) & 1u) << 1)
                          | (((u32)(bal >> 32) & 1u) << 2)
                          | (((u32)(bal >> 48) & 1u) << 3);
                __hip_atomic_store(&lds_spike[g], bits4, __ATOMIC_RELAXED,
                                   __HIP_MEMORY_SCOPE_WORKGROUP);
                old = __hip_atomic_fetch_add(&lds_cnt[s], 1, __ATOMIC_ACQ_REL,
                                             __HIP_MEMORY_SCOPE_WORKGROUP);
            }
            old = __shfl(old, 0, 64);
            if (old == 7) {                      // 8th (last) compute wave
                u32 b = (lane < 8) ? ((lds_spike[lane] & 0xFu) << (4 * lane)) : 0u;
                b |= __shfl_xor(b, 1, 64);
                b |= __shfl_xor(b, 2, 64);
                b |= __shfl_xor(b, 4, 64);
                if (lane == 0)
                    pub_store(&fdata[((size_t)((s + 1) & 1) * CBLOCKS + bid) * MBSTRIDE],
                              ((u64)(u32)(s + 2) << 32) | b);
            }

            if (l16 == 0)
                out[(size_t)s * NN + row] = fire ? 1.0f : 0.0f;
        }
    }
}

extern "C" void kernel_launch(void* const* d_in, const int* in_sizes, int n_in,
                              void* d_out, int out_size, void* d_ws, size_t ws_size,
                              hipStream_t stream) {
    const float* W  = (const float*)d_in[0];
    const float* f0 = (const float*)d_in[1];
    const float* v0 = (const float*)d_in[2];
    float* out = (float*)d_out;

    // workspace: padded mailbox only (64 KB); 0xAA poison != any tag 1..66
    u64* fdata = (u64*)d_ws;

    spiking_fused<<<dim3(CBLOCKS), dim3(STHREADS), 0, stream>>>(
        W, f0, v0, out, fdata);
}